// Round 10
// baseline (278.988 us; speedup 1.0000x reference)
//
#include <hip/hip_runtime.h>
#include <hip/hip_bf16.h>
#include <math.h>

typedef __bf16 bf16x8 __attribute__((ext_vector_type(8)));
typedef float  f32x4  __attribute__((ext_vector_type(4)));
typedef short  s16x4  __attribute__((ext_vector_type(4)));
typedef unsigned int u32x2 __attribute__((ext_vector_type(2)));

#define B_   4
#define N_   2048
#define C_   512
#define H_   8
#define DH_  64
#define HID_ 2048
#define MTOK 8192
#define LOG2E 1.4426950408889634f
#define QSCALE 0.18033688011112042f   // 0.125 * log2(e), folded into Q store

__device__ inline void gld_lds16(const void* g, void* l) {
  __builtin_amdgcn_global_load_lds((const __attribute__((address_space(1))) void*)g,
                                   (__attribute__((address_space(3))) void*)l,
                                   16, 0, 0);
}

// round-half-up f32->bf16 pack via v_perm: 3 VALU per pair
__device__ inline unsigned pack2_bf16(float a, float b) {
  unsigned pa = __builtin_bit_cast(unsigned, a) + 0x8000u;
  unsigned pb = __builtin_bit_cast(unsigned, b) + 0x8000u;
  return __builtin_amdgcn_perm(pb, pa, 0x07060302u);  // lo16=pa.hi, hi16=pb.hi
}

// ---------------- C = A[M,K] * B[N,K]^T, 512-thr, 1-barrier dbuf K-loop -------
// 8 waves; BN=128: wave tile 32x64 (acc 2x4); BN=64: 32x32 (acc 2x2).
// 1D grid, bn-fastest: consecutive blocks share the A-tile; round-robin XCD
// assignment pins each B-strip in one XCD's L2 (B <= 2MB < 4MB).
// __launch_bounds__(512,6): VGPR<=85 -> 3 blocks/CU (24 waves).
// EPI 0: qkv split-store: q (x QSCALE), k -> [b,h,n,d]; v -> V^T [b,h,d,n]
// EPI 1: fout = acc + bias[col] + resid  (fp32)
// EPI 2: bout = gelu(acc + bias[col])    (bf16, tanh-form via exp2)
template<int EPI, int BN>
__global__ __launch_bounds__(512, 6) void gemm512(
    const __bf16* __restrict__ A, const __bf16* __restrict__ Bw,
    int M, int N, int K, int nby,
    const float* __restrict__ bias, const float* __restrict__ resid,
    float* __restrict__ fout, __bf16* __restrict__ bout,
    __bf16* __restrict__ qo, __bf16* __restrict__ ko, __bf16* __restrict__ vo)
{
  constexpr int NT = (BN == 128) ? 4 : 2;
  __shared__ __align__(16) __bf16 a_lds[2][128 * 32];
  __shared__ __align__(16) __bf16 b_lds[2][BN * 32];
  const int tid  = threadIdx.x;
  const int wave = tid >> 6, lane = tid & 63;
  const int quad = lane >> 4, l16 = lane & 15;
  const int bid  = blockIdx.x;
  const int bm = (bid / nby) * 128, bn = (bid % nby) * BN;
  const int wr = (wave >> 1) * 32;
  const int wc = (wave & 1) * (BN == 128 ? 64 : 32);
  const int srow = tid >> 2;        // 0..127 staging row
  const int c4   = lane & 3;        // 16B chunk

  const f32x4 fzero = {0.f, 0.f, 0.f, 0.f};
  f32x4 acc[2][NT];
  #pragma unroll
  for (int i = 0; i < 2; ++i)
    #pragma unroll
    for (int j = 0; j < NT; ++j) acc[i][j] = fzero;

  auto stage = [&](int buf, int k0) {
    gld_lds16(A + (size_t)(bm + srow) * K + k0 + c4 * 8, &a_lds[buf][wave * 512]);
    if (BN == 128 || wave < 4)
      gld_lds16(Bw + (size_t)(bn + srow) * K + k0 + c4 * 8, &b_lds[buf][wave * 512]);
  };

  const int nk = K >> 5;
  stage(0, 0);
  for (int ki = 0; ki < nk; ++ki) {
    const int cur = ki & 1;
    __syncthreads();
    if (ki + 1 < nk) stage(cur ^ 1, (ki + 1) << 5);
    bf16x8 af[2], bf[NT];
    #pragma unroll
    for (int t = 0; t < 2; ++t)
      af[t] = *(const bf16x8*)&a_lds[cur][(wr + t * 16 + l16) * 32 + quad * 8];
    #pragma unroll
    for (int t = 0; t < NT; ++t)
      bf[t] = *(const bf16x8*)&b_lds[cur][(wc + t * 16 + l16) * 32 + quad * 8];
    #pragma unroll
    for (int mt = 0; mt < 2; ++mt)
      #pragma unroll
      for (int nt = 0; nt < NT; ++nt)
        acc[mt][nt] = __builtin_amdgcn_mfma_f32_16x16x32_bf16(af[mt], bf[nt], acc[mt][nt], 0, 0, 0);
  }

  #pragma unroll
  for (int mt = 0; mt < 2; ++mt) {
    #pragma unroll
    for (int nt = 0; nt < NT; ++nt) {
      #pragma unroll
      for (int r = 0; r < 4; ++r) {
        const int row = bm + wr + mt * 16 + quad * 4 + r;
        const int col = bn + wc + nt * 16 + l16;
        float v = acc[mt][nt][r];
        if (EPI == 0) {
          const int b = row >> 11, n = row & (N_ - 1);
          const int s = col >> 9, h = (col >> 6) & (H_ - 1), d = col & (DH_ - 1);
          if (s == 2) {
            vo[((((size_t)b * H_ + h) * DH_ + d) << 11) + n] = (__bf16)v;
          } else if (s == 1) {
            ko[((((size_t)b * H_ + h) * N_ + n) << 6) + d] = (__bf16)v;
          } else {
            qo[((((size_t)b * H_ + h) * N_ + n) << 6) + d] = (__bf16)(v * QSCALE);
          }
        } else if (EPI == 1) {
          const size_t idx = (size_t)row * N + col;
          fout[idx] = v + bias[col] + resid[idx];
        } else {
          // gelu, tanh form: g = x * t / (t + 1), t = exp2(2*c*log2e*(x + 0.044715x^3))
          const float xg = v + bias[col];
          const float x2 = xg * xg;
          const float u  = __builtin_fmaf(0.044715f * x2, xg, xg);
          const float t  = __builtin_amdgcn_exp2f(u * 2.3022082f);
          const float g  = xg * t * __builtin_amdgcn_rcpf(t + 1.0f);
          bout[(size_t)row * N + col] = (__bf16)g;
        }
      }
    }
  }
}

// ---------------- LayerNorm device helper: one wave per token -----------------
__device__ inline void ln_row(const float* __restrict__ xr,
                              const float* __restrict__ w, const float* __restrict__ b,
                              __bf16* __restrict__ orow, int lane)
{
  float4 v0 = ((const float4*)xr)[lane];
  float4 v1 = ((const float4*)xr)[lane + 64];
  float s = v0.x + v0.y + v0.z + v0.w + v1.x + v1.y + v1.z + v1.w;
  float q = v0.x*v0.x + v0.y*v0.y + v0.z*v0.z + v0.w*v0.w
          + v1.x*v1.x + v1.y*v1.y + v1.z*v1.z + v1.w*v1.w;
  #pragma unroll
  for (int off = 32; off >= 1; off >>= 1) {
    s += __shfl_xor(s, off, 64);
    q += __shfl_xor(q, off, 64);
  }
  const float mu  = s * (1.0f / C_);
  const float var = q * (1.0f / C_) - mu * mu;
  const float rs  = rsqrtf(var + 1e-5f);
  float4 w0 = ((const float4*)w)[lane], w1 = ((const float4*)w)[lane + 64];
  float4 b0 = ((const float4*)b)[lane], b1 = ((const float4*)b)[lane + 64];
  const int c0 = lane * 4;
  orow[c0 + 0]       = (__bf16)((v0.x - mu) * rs * w0.x + b0.x);
  orow[c0 + 1]       = (__bf16)((v0.y - mu) * rs * w0.y + b0.y);
  orow[c0 + 2]       = (__bf16)((v0.z - mu) * rs * w0.z + b0.z);
  orow[c0 + 3]       = (__bf16)((v0.w - mu) * rs * w0.w + b0.w);
  orow[256 + c0 + 0] = (__bf16)((v1.x - mu) * rs * w1.x + b1.x);
  orow[256 + c0 + 1] = (__bf16)((v1.y - mu) * rs * w1.y + b1.y);
  orow[256 + c0 + 2] = (__bf16)((v1.z - mu) * rs * w1.z + b1.z);
  orow[256 + c0 + 3] = (__bf16)((v1.w - mu) * rs * w1.w + b1.w);
}

// ---------------- standalone LN (for ln2) -------------------------------------
__global__ __launch_bounds__(256) void ln_kernel(
    const float* __restrict__ x, const float* __restrict__ w,
    const float* __restrict__ b, __bf16* __restrict__ out)
{
  const int wave = threadIdx.x >> 6, lane = threadIdx.x & 63;
  const int tok  = blockIdx.x * 4 + wave;
  ln_row(x + (size_t)tok * C_, w, b, out + (size_t)tok * C_, lane);
}

// ---------------- merged: weight cast (blocks 0..3071) + ln1 (3072..5119) -----
__global__ __launch_bounds__(256) void castln_kernel(
    const float* __restrict__ s0, const float* __restrict__ s1,
    const float* __restrict__ s2, const float* __restrict__ s3,
    __bf16* __restrict__ d0, __bf16* __restrict__ d1,
    __bf16* __restrict__ d2, __bf16* __restrict__ d3,
    const float* __restrict__ x, const float* __restrict__ n1w,
    const float* __restrict__ n1b, __bf16* __restrict__ hbuf)
{
  if (blockIdx.x < 3072) {
    const int i = (blockIdx.x * 256 + threadIdx.x) * 4;
    const float* s; __bf16* d; int off;
    if (i < 786432)       { s = s0; d = d0; off = i; }
    else if (i < 1048576) { s = s1; d = d1; off = i - 786432; }
    else if (i < 2097152) { s = s2; d = d2; off = i - 1048576; }
    else                  { s = s3; d = d3; off = i - 2097152; }
    const float4 v = *(const float4*)(s + off);
    u32x2 pk;
    pk.x = pack2_bf16(v.x, v.y);
    pk.y = pack2_bf16(v.z, v.w);
    *(u32x2*)(d + off) = pk;
  } else {
    const int wave = threadIdx.x >> 6, lane = threadIdx.x & 63;
    const int tok  = (blockIdx.x - 3072) * 4 + wave;
    ln_row(x + (size_t)tok * C_, n1w, n1b, hbuf + (size_t)tok * C_, lane);
  }
}

// ---------------- flash attention v8: VALU-diet (unchanged from R8/R9) --------
__global__ __launch_bounds__(256, 3) void flash_kernel(
    const __bf16* __restrict__ qb, const __bf16* __restrict__ kb,
    const __bf16* __restrict__ vtg, const float* __restrict__ rpb,
    __bf16* __restrict__ outb)
{
  __shared__ __align__(16) __bf16 kbuf[8192];       // [2 ks][128 key][32 d]
  __shared__ __align__(16) __bf16 vbuf[8192];       // [4 ks2][64 d][32 key], granule-swizzled
  __shared__ __align__(16) __bf16 biasC[2][2192];   // copy a: bias[i - a], *LOG2E
  const int tid  = threadIdx.x;
  const int wave = tid >> 6, lane = tid & 63;
  const int quad = lane >> 4, l16 = lane & 15;
  const int bh = blockIdx.y, h = bh & (H_ - 1);
  const int q0 = blockIdx.x * 128;
  const int boff = 1920 - q0;

  #pragma unroll
  for (int a = 0; a < 2; ++a)
    for (int i = tid; i < 2192; i += 256) {
      int ridx = i - a + boff;
      ridx = ridx < 0 ? 0 : (ridx > 2 * N_ - 2 ? 2 * N_ - 2 : ridx);
      biasC[a][i] = (__bf16)(rpb[(size_t)ridx * H_ + h] * LOG2E);
    }

  const __bf16* qptr = qb  + (size_t)bh * N_ * DH_;
  const __bf16* kptr = kb  + (size_t)bh * N_ * DH_;
  const __bf16* vtp  = vtg + (size_t)bh * N_ * DH_;

  bf16x8 qf[2][2];
  #pragma unroll
  for (int mt = 0; mt < 2; ++mt)
    #pragma unroll
    for (int ks = 0; ks < 2; ++ks)
      qf[mt][ks] = *(const bf16x8*)(qptr +
          (size_t)(q0 + wave * 32 + mt * 16 + l16) * DH_ + ks * 32 + quad * 8);

  const f32x4 fzero = {0.f, 0.f, 0.f, 0.f};
  f32x4 o[2][4];
  f32x4 la[2] = {fzero, fzero};     // l accumulators (ones-MFMA)
  #pragma unroll
  for (int mt = 0; mt < 2; ++mt)
    #pragma unroll
    for (int dt = 0; dt < 4; ++dt) o[mt][dt] = fzero;

  const short one_bf16 = (short)0x3F80;
  const s16x4 ones = {one_bf16, one_bf16, one_bf16, one_bf16};

  const int slr = lane >> 2;
  const int slc = lane & 3;
  const int vswz = (slr & 3) ^ ((slr >> 2) & 3);

  auto stageK = [&](int kcn) {
    #pragma unroll
    for (int j = 0; j < 4; ++j) {
      const int idx = wave * 4 + j;
      const int ks = idx & 1, g = idx >> 1;
      gld_lds16(kptr + (size_t)(kcn + g * 16 + slr) * DH_ + ks * 32 + slc * 8,
                &kbuf[ks * 4096 + g * 512]);
    }
  };
  auto stageV = [&](int kcn) {
    #pragma unroll
    for (int j = 0; j < 4; ++j) {
      const int idx = wave * 4 + j;
      const int ks2 = idx & 3, gg = idx >> 2;
      gld_lds16(vtp + (size_t)(gg * 16 + slr) * N_ + kcn + ks2 * 32 + (slc ^ vswz) * 8,
                &vbuf[ks2 * 2048 + gg * 512]);
    }
  };

  const int bb0 = 127 + quad * 4 - wave * 32 - l16;
  const int acp = bb0 & 1;
  const __bf16* bcp = &biasC[acp][acp];

  for (int it = 0; it < 16; ++it) {
    const int kc = it << 7;
    __syncthreads();                 // prior iter reads (and bias fill) done
    stageK(kc);
    stageV(kc);
    __syncthreads();                 // K,V visible

    unsigned pk[2][8][2];
    const __bf16* bp = bcp + kc + bb0;
    #pragma unroll
    for (int ct = 0; ct < 8; ++ct) {
      const bf16x8 kf0 = *(const bf16x8*)&kbuf[(ct * 16 + l16) * 32 + quad * 8];
      const bf16x8 kf1 = *(const bf16x8*)&kbuf[4096 + (ct * 16 + l16) * 32 + quad * 8];
      const unsigned w0 = *(const unsigned*)(bp + ct * 16);
      const unsigned w1 = *(const unsigned*)(bp + ct * 16 + 2);
      const unsigned x0 = *(const unsigned*)(bp + ct * 16 - 16);
      const unsigned x1 = *(const unsigned*)(bp + ct * 16 - 14);
      const f32x4 c0 = {__builtin_bit_cast(float, w0 << 16),
                        __builtin_bit_cast(float, w0 & 0xFFFF0000u),
                        __builtin_bit_cast(float, w1 << 16),
                        __builtin_bit_cast(float, w1 & 0xFFFF0000u)};
      const f32x4 c1 = {__builtin_bit_cast(float, x0 << 16),
                        __builtin_bit_cast(float, x0 & 0xFFFF0000u),
                        __builtin_bit_cast(float, x1 << 16),
                        __builtin_bit_cast(float, x1 & 0xFFFF0000u)};
      f32x4 s0 = __builtin_amdgcn_mfma_f32_16x16x32_bf16(kf0, qf[0][0], c0, 0, 0, 0);
      s0 = __builtin_amdgcn_mfma_f32_16x16x32_bf16(kf1, qf[0][1], s0, 0, 0, 0);
      f32x4 s1 = __builtin_amdgcn_mfma_f32_16x16x32_bf16(kf0, qf[1][0], c1, 0, 0, 0);
      s1 = __builtin_amdgcn_mfma_f32_16x16x32_bf16(kf1, qf[1][1], s1, 0, 0, 0);
      {
        const float p0 = __builtin_amdgcn_exp2f(s0[0]);
        const float p1 = __builtin_amdgcn_exp2f(s0[1]);
        const float p2 = __builtin_amdgcn_exp2f(s0[2]);
        const float p3 = __builtin_amdgcn_exp2f(s0[3]);
        pk[0][ct][0] = pack2_bf16(p0, p1);
        pk[0][ct][1] = pack2_bf16(p2, p3);
      }
      {
        const float p0 = __builtin_amdgcn_exp2f(s1[0]);
        const float p1 = __builtin_amdgcn_exp2f(s1[1]);
        const float p2 = __builtin_amdgcn_exp2f(s1[2]);
        const float p3 = __builtin_amdgcn_exp2f(s1[3]);
        pk[1][ct][0] = pack2_bf16(p0, p1);
        pk[1][ct][1] = pack2_bf16(p2, p3);
      }
    }

    #pragma unroll
    for (int ct = 0; ct < 8; ++ct) {
      const int gran = ((ct & 1) * 2 + (quad >> 1)) ^ ((l16 & 3) ^ ((l16 >> 2) & 3));
      const int vbase = (ct >> 1) * 2048 + l16 * 32 + gran * 8 + (quad & 1) * 4;
      const s16x4 pf0 = __builtin_bit_cast(s16x4, u32x2{pk[0][ct][0], pk[0][ct][1]});
      const s16x4 pf1 = __builtin_bit_cast(s16x4, u32x2{pk[1][ct][0], pk[1][ct][1]});
      la[0] = __builtin_amdgcn_mfma_f32_16x16x16bf16_1k(ones, pf0, la[0], 0, 0, 0);
      la[1] = __builtin_amdgcn_mfma_f32_16x16x16bf16_1k(ones, pf1, la[1], 0, 0, 0);
      #pragma unroll
      for (int dt = 0; dt < 4; ++dt) {
        const s16x4 vf = *(const s16x4*)&vbuf[vbase + dt * 512];
        o[0][dt] = __builtin_amdgcn_mfma_f32_16x16x16bf16_1k(vf, pf0, o[0][dt], 0, 0, 0);
        o[1][dt] = __builtin_amdgcn_mfma_f32_16x16x16bf16_1k(vf, pf1, o[1][dt], 0, 0, 0);
      }
    }
  }

  const int b = bh >> 3;
  #pragma unroll
  for (int mt = 0; mt < 2; ++mt) {
    const float inv = 1.0f / la[mt][0];
    const int qg = q0 + wave * 32 + mt * 16 + l16;
    __bf16* orow = outb + ((size_t)(b * N_ + qg)) * C_ + h * DH_ + quad * 4;
    #pragma unroll
    for (int dt = 0; dt < 4; ++dt) {
      u32x2 pkd;
      pkd.x = pack2_bf16(o[mt][dt][0] * inv, o[mt][dt][1] * inv);
      pkd.y = pack2_bf16(o[mt][dt][2] * inv, o[mt][dt][3] * inv);
      *(u32x2*)(orow + dt * 16) = pkd;
    }
  }
}

extern "C" void kernel_launch(void* const* d_in, const int* in_sizes, int n_in,
                              void* d_out, int out_size, void* d_ws, size_t ws_size,
                              hipStream_t stream)
{
  const float* x      = (const float*)d_in[0];
  const float* qkv_w  = (const float*)d_in[1];
  const float* proj_w = (const float*)d_in[2];
  const float* proj_b = (const float*)d_in[3];
  const float* rpb    = (const float*)d_in[4];
  const float* n1w    = (const float*)d_in[5];
  const float* n1b    = (const float*)d_in[6];
  const float* n2w    = (const float*)d_in[7];
  const float* n2b    = (const float*)d_in[8];
  const float* fc1_w  = (const float*)d_in[9];
  const float* fc1_b  = (const float*)d_in[10];
  const float* fc2_w  = (const float*)d_in[11];
  const float* fc2_b  = (const float*)d_in[12];

  char* ws = (char*)d_ws;
  __bf16* hbuf = (__bf16*)(ws + 0);          // 8192*512  bf16
  __bf16* qbuf = (__bf16*)(ws + 8388608);    // [b,h,n,d] (pre-scaled by QSCALE)
  __bf16* kbuf = (__bf16*)(ws + 16777216);   // [b,h,n,d]
  __bf16* vbuf = (__bf16*)(ws + 25165824);   // V^T [b,h,d,n]
  __bf16* gelu = (__bf16*)(ws + 0);          // 8192*2048 bf16 (alias)
  __bf16* wq   = (__bf16*)(ws + 33554432);
  __bf16* wp   = (__bf16*)(ws + 35127296);
  __bf16* w1   = (__bf16*)(ws + 35651584);
  __bf16* w2   = (__bf16*)(ws + 37748736);
  __bf16* attn = (__bf16*)(ws + 39845888);   // 8192*512 bf16
  __bf16* h2in = attn;                       // alias
  float*  x1   = (float*)(ws + 48234496);    // 8192*512 fp32
  float*  outp = (float*)d_out;

  // cast (3072 blocks) + ln1 (2048 blocks) in one launch
  castln_kernel<<<5120, 256, 0, stream>>>(qkv_w, proj_w, fc1_w, fc2_w,
      wq, wp, w1, w2, x, n1w, n1b, hbuf);

  gemm512<0, 128><<<64 * 12, 512, 0, stream>>>(hbuf, wq, MTOK, 1536, 512, 12,
      nullptr, nullptr, nullptr, nullptr, qbuf, kbuf, vbuf);

  flash_kernel<<<dim3(16, 32), 256, 0, stream>>>(qbuf, kbuf, vbuf, rpb, attn);

  gemm512<1, 64><<<64 * 8, 512, 0, stream>>>(attn, wp, MTOK, 512, 512, 8,
      proj_b, x, x1, nullptr, nullptr, nullptr, nullptr);

  ln_kernel<<<2048, 256, 0, stream>>>(x1, n2w, n2b, h2in);

  gemm512<2, 128><<<64 * 16, 512, 0, stream>>>(h2in, w1, MTOK, 2048, 512, 16,
      fc1_b, nullptr, nullptr, gelu, nullptr, nullptr, nullptr);

  gemm512<1, 64><<<64 * 8, 512, 0, stream>>>(gelu, w2, MTOK, 512, 2048, 8,
      fc2_b, x1, outp, nullptr, nullptr, nullptr, nullptr);
}

// Round 11
// 258.794 us; speedup vs baseline: 1.0780x; 1.0780x over previous
//
#include <hip/hip_runtime.h>
#include <hip/hip_bf16.h>
#include <math.h>

typedef __bf16 bf16x8 __attribute__((ext_vector_type(8)));
typedef float  f32x4  __attribute__((ext_vector_type(4)));
typedef short  s16x4  __attribute__((ext_vector_type(4)));
typedef unsigned int u32x2 __attribute__((ext_vector_type(2)));

#define B_   4
#define N_   2048
#define C_   512
#define H_   8
#define DH_  64
#define HID_ 2048
#define MTOK 8192
#define LOG2E 1.4426950408889634f
#define QSCALE 0.18033688011112042f   // 0.125 * log2(e), folded into Q store

__device__ inline void gld_lds16(const void* g, void* l) {
  __builtin_amdgcn_global_load_lds((const __attribute__((address_space(1))) void*)g,
                                   (__attribute__((address_space(3))) void*)l,
                                   16, 0, 0);
}

// round-half-up f32->bf16 pack via v_perm: 3 VALU per pair
__device__ inline unsigned pack2_bf16(float a, float b) {
  unsigned pa = __builtin_bit_cast(unsigned, a) + 0x8000u;
  unsigned pb = __builtin_bit_cast(unsigned, b) + 0x8000u;
  return __builtin_amdgcn_perm(pb, pa, 0x07060302u);  // lo16=pa.hi, hi16=pb.hi
}

// ---------------- C = A[M,K] * B[N,K]^T, 512-thr, 1-barrier dbuf K-loop -------
// R9 config (launch_bounds(512,4), 2D grid x-fastest) — R10's (512,6)+1D grid
// regressed 17us (VGPR clamp spills + worse L2 order). Do not re-apply.
// EPI 0: qkv split-store: q (x QSCALE), k -> [b,h,n,d]; v -> V^T [b,h,d,n]
// EPI 1: fout = acc + bias[col] + resid  (fp32)
// EPI 2: bout = gelu(acc + bias[col])    (bf16, tanh-form via exp2)
template<int EPI, int BN>
__global__ __launch_bounds__(512, 4) void gemm512(
    const __bf16* __restrict__ A, const __bf16* __restrict__ Bw,
    int M, int N, int K,
    const float* __restrict__ bias, const float* __restrict__ resid,
    float* __restrict__ fout, __bf16* __restrict__ bout,
    __bf16* __restrict__ qo, __bf16* __restrict__ ko, __bf16* __restrict__ vo)
{
  constexpr int NT = (BN == 128) ? 4 : 2;
  __shared__ __align__(16) __bf16 a_lds[2][128 * 32];
  __shared__ __align__(16) __bf16 b_lds[2][BN * 32];
  const int tid  = threadIdx.x;
  const int wave = tid >> 6, lane = tid & 63;
  const int quad = lane >> 4, l16 = lane & 15;
  const int bm = blockIdx.x * 128, bn = blockIdx.y * BN;
  const int wr = (wave >> 1) * 32;
  const int wc = (wave & 1) * (BN == 128 ? 64 : 32);
  const int srow = tid >> 2;        // 0..127 staging row
  const int c4   = lane & 3;        // 16B chunk

  const f32x4 fzero = {0.f, 0.f, 0.f, 0.f};
  f32x4 acc[2][NT];
  #pragma unroll
  for (int i = 0; i < 2; ++i)
    #pragma unroll
    for (int j = 0; j < NT; ++j) acc[i][j] = fzero;

  auto stage = [&](int buf, int k0) {
    gld_lds16(A + (size_t)(bm + srow) * K + k0 + c4 * 8, &a_lds[buf][wave * 512]);
    if (BN == 128 || wave < 4)
      gld_lds16(Bw + (size_t)(bn + srow) * K + k0 + c4 * 8, &b_lds[buf][wave * 512]);
  };

  const int nk = K >> 5;
  stage(0, 0);
  for (int ki = 0; ki < nk; ++ki) {
    const int cur = ki & 1;
    __syncthreads();
    if (ki + 1 < nk) stage(cur ^ 1, (ki + 1) << 5);
    bf16x8 af[2], bf[NT];
    #pragma unroll
    for (int t = 0; t < 2; ++t)
      af[t] = *(const bf16x8*)&a_lds[cur][(wr + t * 16 + l16) * 32 + quad * 8];
    #pragma unroll
    for (int t = 0; t < NT; ++t)
      bf[t] = *(const bf16x8*)&b_lds[cur][(wc + t * 16 + l16) * 32 + quad * 8];
    #pragma unroll
    for (int mt = 0; mt < 2; ++mt)
      #pragma unroll
      for (int nt = 0; nt < NT; ++nt)
        acc[mt][nt] = __builtin_amdgcn_mfma_f32_16x16x32_bf16(af[mt], bf[nt], acc[mt][nt], 0, 0, 0);
  }

  #pragma unroll
  for (int mt = 0; mt < 2; ++mt) {
    #pragma unroll
    for (int nt = 0; nt < NT; ++nt) {
      #pragma unroll
      for (int r = 0; r < 4; ++r) {
        const int row = bm + wr + mt * 16 + quad * 4 + r;
        const int col = bn + wc + nt * 16 + l16;
        float v = acc[mt][nt][r];
        if (EPI == 0) {
          const int b = row >> 11, n = row & (N_ - 1);
          const int s = col >> 9, h = (col >> 6) & (H_ - 1), d = col & (DH_ - 1);
          if (s == 2) {
            vo[((((size_t)b * H_ + h) * DH_ + d) << 11) + n] = (__bf16)v;
          } else if (s == 1) {
            ko[((((size_t)b * H_ + h) * N_ + n) << 6) + d] = (__bf16)v;
          } else {
            qo[((((size_t)b * H_ + h) * N_ + n) << 6) + d] = (__bf16)(v * QSCALE);
          }
        } else if (EPI == 1) {
          const size_t idx = (size_t)row * N + col;
          fout[idx] = v + bias[col] + resid[idx];
        } else {
          // gelu, tanh form: g = x * t / (t + 1), t = exp2(2*c*log2e*(x + 0.044715x^3))
          const float xg = v + bias[col];
          const float x2 = xg * xg;
          const float u  = __builtin_fmaf(0.044715f * x2, xg, xg);
          const float t  = __builtin_amdgcn_exp2f(u * 2.3022082f);
          const float g  = xg * t * __builtin_amdgcn_rcpf(t + 1.0f);
          bout[(size_t)row * N + col] = (__bf16)g;
        }
      }
    }
  }
}

// ---------------- LayerNorm device helper: one wave per token -----------------
__device__ inline void ln_row(const float* __restrict__ xr,
                              const float* __restrict__ w, const float* __restrict__ b,
                              __bf16* __restrict__ orow, int lane)
{
  float4 v0 = ((const float4*)xr)[lane];
  float4 v1 = ((const float4*)xr)[lane + 64];
  float s = v0.x + v0.y + v0.z + v0.w + v1.x + v1.y + v1.z + v1.w;
  float q = v0.x*v0.x + v0.y*v0.y + v0.z*v0.z + v0.w*v0.w
          + v1.x*v1.x + v1.y*v1.y + v1.z*v1.z + v1.w*v1.w;
  #pragma unroll
  for (int off = 32; off >= 1; off >>= 1) {
    s += __shfl_xor(s, off, 64);
    q += __shfl_xor(q, off, 64);
  }
  const float mu  = s * (1.0f / C_);
  const float var = q * (1.0f / C_) - mu * mu;
  const float rs  = rsqrtf(var + 1e-5f);
  float4 w0 = ((const float4*)w)[lane], w1 = ((const float4*)w)[lane + 64];
  float4 b0 = ((const float4*)b)[lane], b1 = ((const float4*)b)[lane + 64];
  const int c0 = lane * 4;
  orow[c0 + 0]       = (__bf16)((v0.x - mu) * rs * w0.x + b0.x);
  orow[c0 + 1]       = (__bf16)((v0.y - mu) * rs * w0.y + b0.y);
  orow[c0 + 2]       = (__bf16)((v0.z - mu) * rs * w0.z + b0.z);
  orow[c0 + 3]       = (__bf16)((v0.w - mu) * rs * w0.w + b0.w);
  orow[256 + c0 + 0] = (__bf16)((v1.x - mu) * rs * w1.x + b1.x);
  orow[256 + c0 + 1] = (__bf16)((v1.y - mu) * rs * w1.y + b1.y);
  orow[256 + c0 + 2] = (__bf16)((v1.z - mu) * rs * w1.z + b1.z);
  orow[256 + c0 + 3] = (__bf16)((v1.w - mu) * rs * w1.w + b1.w);
}

// ---------------- standalone LN (for ln2) -------------------------------------
__global__ __launch_bounds__(256) void ln_kernel(
    const float* __restrict__ x, const float* __restrict__ w,
    const float* __restrict__ b, __bf16* __restrict__ out)
{
  const int wave = threadIdx.x >> 6, lane = threadIdx.x & 63;
  const int tok  = blockIdx.x * 4 + wave;
  ln_row(x + (size_t)tok * C_, w, b, out + (size_t)tok * C_, lane);
}

// ---------------- merged: weight cast (blocks 0..3071) + ln1 (3072..5119) -----
__global__ __launch_bounds__(256) void castln_kernel(
    const float* __restrict__ s0, const float* __restrict__ s1,
    const float* __restrict__ s2, const float* __restrict__ s3,
    __bf16* __restrict__ d0, __bf16* __restrict__ d1,
    __bf16* __restrict__ d2, __bf16* __restrict__ d3,
    const float* __restrict__ x, const float* __restrict__ n1w,
    const float* __restrict__ n1b, __bf16* __restrict__ hbuf)
{
  if (blockIdx.x < 3072) {
    const int i = (blockIdx.x * 256 + threadIdx.x) * 4;
    const float* s; __bf16* d; int off;
    if (i < 786432)       { s = s0; d = d0; off = i; }
    else if (i < 1048576) { s = s1; d = d1; off = i - 786432; }
    else if (i < 2097152) { s = s2; d = d2; off = i - 1048576; }
    else                  { s = s3; d = d3; off = i - 2097152; }
    const float4 v = *(const float4*)(s + off);
    u32x2 pk;
    pk.x = pack2_bf16(v.x, v.y);
    pk.y = pack2_bf16(v.z, v.w);
    *(u32x2*)(d + off) = pk;
  } else {
    const int wave = threadIdx.x >> 6, lane = threadIdx.x & 63;
    const int tok  = (blockIdx.x - 3072) * 4 + wave;
    ln_row(x + (size_t)tok * C_, n1w, n1b, hbuf + (size_t)tok * C_, lane);
  }
}

// ---------------- flash attention v9: full K+V double-buffer, 1 barrier/iter --
// v8 plus: kbufs/vbufs both double-buffered (LDS 74.3 KB, grid 512 = 2 blk/CU
// so the extra LDS is free). DMAs for iter i+1 issue right after iter i's
// single barrier and have the whole QK+softmax+PV stretch to land -> half the
// vmcnt(0) drains of v8.
__global__ __launch_bounds__(256, 2) void flash_kernel(
    const __bf16* __restrict__ qb, const __bf16* __restrict__ kb,
    const __bf16* __restrict__ vtg, const float* __restrict__ rpb,
    __bf16* __restrict__ outb)
{
  __shared__ __align__(16) __bf16 kbufs[2][8192];   // [buf][2 ks][128 key][32 d]
  __shared__ __align__(16) __bf16 vbufs[2][8192];   // [buf][4 ks2][64 d][32 key], swizzled
  __shared__ __align__(16) __bf16 biasC[2][2192];   // copy a: bias[i - a], *LOG2E
  const int tid  = threadIdx.x;
  const int wave = tid >> 6, lane = tid & 63;
  const int quad = lane >> 4, l16 = lane & 15;
  const int bh = blockIdx.y, h = bh & (H_ - 1);
  const int q0 = blockIdx.x * 128;
  const int boff = 1920 - q0;

  #pragma unroll
  for (int a = 0; a < 2; ++a)
    for (int i = tid; i < 2192; i += 256) {
      int ridx = i - a + boff;
      ridx = ridx < 0 ? 0 : (ridx > 2 * N_ - 2 ? 2 * N_ - 2 : ridx);
      biasC[a][i] = (__bf16)(rpb[(size_t)ridx * H_ + h] * LOG2E);
    }

  const __bf16* qptr = qb  + (size_t)bh * N_ * DH_;
  const __bf16* kptr = kb  + (size_t)bh * N_ * DH_;
  const __bf16* vtp  = vtg + (size_t)bh * N_ * DH_;

  bf16x8 qf[2][2];
  #pragma unroll
  for (int mt = 0; mt < 2; ++mt)
    #pragma unroll
    for (int ks = 0; ks < 2; ++ks)
      qf[mt][ks] = *(const bf16x8*)(qptr +
          (size_t)(q0 + wave * 32 + mt * 16 + l16) * DH_ + ks * 32 + quad * 8);

  const f32x4 fzero = {0.f, 0.f, 0.f, 0.f};
  f32x4 o[2][4];
  f32x4 la[2] = {fzero, fzero};     // l accumulators (ones-MFMA)
  #pragma unroll
  for (int mt = 0; mt < 2; ++mt)
    #pragma unroll
    for (int dt = 0; dt < 4; ++dt) o[mt][dt] = fzero;

  const short one_bf16 = (short)0x3F80;
  const s16x4 ones = {one_bf16, one_bf16, one_bf16, one_bf16};

  const int slr = lane >> 2;
  const int slc = lane & 3;
  const int vswz = (slr & 3) ^ ((slr >> 2) & 3);

  auto stageK = [&](int buf, int kcn) {
    #pragma unroll
    for (int j = 0; j < 4; ++j) {
      const int idx = wave * 4 + j;
      const int ks = idx & 1, g = idx >> 1;
      gld_lds16(kptr + (size_t)(kcn + g * 16 + slr) * DH_ + ks * 32 + slc * 8,
                &kbufs[buf][ks * 4096 + g * 512]);
    }
  };
  auto stageV = [&](int buf, int kcn) {
    #pragma unroll
    for (int j = 0; j < 4; ++j) {
      const int idx = wave * 4 + j;
      const int ks2 = idx & 3, gg = idx >> 2;
      gld_lds16(vtp + (size_t)(gg * 16 + slr) * N_ + kcn + ks2 * 32 + (slc ^ vswz) * 8,
                &vbufs[buf][ks2 * 2048 + gg * 512]);
    }
  };

  const int bb0 = 127 + quad * 4 - wave * 32 - l16;
  const int acp = bb0 & 1;
  const __bf16* bcp = &biasC[acp][acp];

  stageK(0, 0);
  stageV(0, 0);
  for (int it = 0; it < 16; ++it) {
    const int cur = it & 1;
    const int kc = it << 7;
    __syncthreads();   // buf[cur] DMA complete; buf[cur] reads of iter it-2 done
    if (it < 15) {
      stageK(cur ^ 1, kc + 128);
      stageV(cur ^ 1, kc + 128);
    }

    unsigned pk[2][8][2];
    const __bf16* bp = bcp + kc + bb0;
    #pragma unroll
    for (int ct = 0; ct < 8; ++ct) {
      const bf16x8 kf0 = *(const bf16x8*)&kbufs[cur][(ct * 16 + l16) * 32 + quad * 8];
      const bf16x8 kf1 = *(const bf16x8*)&kbufs[cur][4096 + (ct * 16 + l16) * 32 + quad * 8];
      const unsigned w0 = *(const unsigned*)(bp + ct * 16);
      const unsigned w1 = *(const unsigned*)(bp + ct * 16 + 2);
      const unsigned x0 = *(const unsigned*)(bp + ct * 16 - 16);
      const unsigned x1 = *(const unsigned*)(bp + ct * 16 - 14);
      const f32x4 c0 = {__builtin_bit_cast(float, w0 << 16),
                        __builtin_bit_cast(float, w0 & 0xFFFF0000u),
                        __builtin_bit_cast(float, w1 << 16),
                        __builtin_bit_cast(float, w1 & 0xFFFF0000u)};
      const f32x4 c1 = {__builtin_bit_cast(float, x0 << 16),
                        __builtin_bit_cast(float, x0 & 0xFFFF0000u),
                        __builtin_bit_cast(float, x1 << 16),
                        __builtin_bit_cast(float, x1 & 0xFFFF0000u)};
      f32x4 s0 = __builtin_amdgcn_mfma_f32_16x16x32_bf16(kf0, qf[0][0], c0, 0, 0, 0);
      s0 = __builtin_amdgcn_mfma_f32_16x16x32_bf16(kf1, qf[0][1], s0, 0, 0, 0);
      f32x4 s1 = __builtin_amdgcn_mfma_f32_16x16x32_bf16(kf0, qf[1][0], c1, 0, 0, 0);
      s1 = __builtin_amdgcn_mfma_f32_16x16x32_bf16(kf1, qf[1][1], s1, 0, 0, 0);
      {
        const float p0 = __builtin_amdgcn_exp2f(s0[0]);
        const float p1 = __builtin_amdgcn_exp2f(s0[1]);
        const float p2 = __builtin_amdgcn_exp2f(s0[2]);
        const float p3 = __builtin_amdgcn_exp2f(s0[3]);
        pk[0][ct][0] = pack2_bf16(p0, p1);
        pk[0][ct][1] = pack2_bf16(p2, p3);
      }
      {
        const float p0 = __builtin_amdgcn_exp2f(s1[0]);
        const float p1 = __builtin_amdgcn_exp2f(s1[1]);
        const float p2 = __builtin_amdgcn_exp2f(s1[2]);
        const float p3 = __builtin_amdgcn_exp2f(s1[3]);
        pk[1][ct][0] = pack2_bf16(p0, p1);
        pk[1][ct][1] = pack2_bf16(p2, p3);
      }
    }

    #pragma unroll
    for (int ct = 0; ct < 8; ++ct) {
      const int gran = ((ct & 1) * 2 + (quad >> 1)) ^ ((l16 & 3) ^ ((l16 >> 2) & 3));
      const int vbase = (ct >> 1) * 2048 + l16 * 32 + gran * 8 + (quad & 1) * 4;
      const s16x4 pf0 = __builtin_bit_cast(s16x4, u32x2{pk[0][ct][0], pk[0][ct][1]});
      const s16x4 pf1 = __builtin_bit_cast(s16x4, u32x2{pk[1][ct][0], pk[1][ct][1]});
      la[0] = __builtin_amdgcn_mfma_f32_16x16x16bf16_1k(ones, pf0, la[0], 0, 0, 0);
      la[1] = __builtin_amdgcn_mfma_f32_16x16x16bf16_1k(ones, pf1, la[1], 0, 0, 0);
      #pragma unroll
      for (int dt = 0; dt < 4; ++dt) {
        const s16x4 vf = *(const s16x4*)&vbufs[cur][vbase + dt * 512];
        o[0][dt] = __builtin_amdgcn_mfma_f32_16x16x16bf16_1k(vf, pf0, o[0][dt], 0, 0, 0);
        o[1][dt] = __builtin_amdgcn_mfma_f32_16x16x16bf16_1k(vf, pf1, o[1][dt], 0, 0, 0);
      }
    }
  }

  const int b = bh >> 3;
  #pragma unroll
  for (int mt = 0; mt < 2; ++mt) {
    const float inv = 1.0f / la[mt][0];
    const int qg = q0 + wave * 32 + mt * 16 + l16;
    __bf16* orow = outb + ((size_t)(b * N_ + qg)) * C_ + h * DH_ + quad * 4;
    #pragma unroll
    for (int dt = 0; dt < 4; ++dt) {
      u32x2 pkd;
      pkd.x = pack2_bf16(o[mt][dt][0] * inv, o[mt][dt][1] * inv);
      pkd.y = pack2_bf16(o[mt][dt][2] * inv, o[mt][dt][3] * inv);
      *(u32x2*)(orow + dt * 16) = pkd;
    }
  }
}

extern "C" void kernel_launch(void* const* d_in, const int* in_sizes, int n_in,
                              void* d_out, int out_size, void* d_ws, size_t ws_size,
                              hipStream_t stream)
{
  const float* x      = (const float*)d_in[0];
  const float* qkv_w  = (const float*)d_in[1];
  const float* proj_w = (const float*)d_in[2];
  const float* proj_b = (const float*)d_in[3];
  const float* rpb    = (const float*)d_in[4];
  const float* n1w    = (const float*)d_in[5];
  const float* n1b    = (const float*)d_in[6];
  const float* n2w    = (const float*)d_in[7];
  const float* n2b    = (const float*)d_in[8];
  const float* fc1_w  = (const float*)d_in[9];
  const float* fc1_b  = (const float*)d_in[10];
  const float* fc2_w  = (const float*)d_in[11];
  const float* fc2_b  = (const float*)d_in[12];

  char* ws = (char*)d_ws;
  __bf16* hbuf = (__bf16*)(ws + 0);          // 8192*512  bf16
  __bf16* qbuf = (__bf16*)(ws + 8388608);    // [b,h,n,d] (pre-scaled by QSCALE)
  __bf16* kbuf = (__bf16*)(ws + 16777216);   // [b,h,n,d]
  __bf16* vbuf = (__bf16*)(ws + 25165824);   // V^T [b,h,d,n]
  __bf16* gelu = (__bf16*)(ws + 0);          // 8192*2048 bf16 (alias)
  __bf16* wq   = (__bf16*)(ws + 33554432);
  __bf16* wp   = (__bf16*)(ws + 35127296);
  __bf16* w1   = (__bf16*)(ws + 35651584);
  __bf16* w2   = (__bf16*)(ws + 37748736);
  __bf16* attn = (__bf16*)(ws + 39845888);   // 8192*512 bf16
  __bf16* h2in = attn;                       // alias
  float*  x1   = (float*)(ws + 48234496);    // 8192*512 fp32
  float*  outp = (float*)d_out;

  // cast (3072 blocks) + ln1 (2048 blocks) in one launch
  castln_kernel<<<5120, 256, 0, stream>>>(qkv_w, proj_w, fc1_w, fc2_w,
      wq, wp, w1, w2, x, n1w, n1b, hbuf);

  gemm512<0, 128><<<dim3(64, 12), 512, 0, stream>>>(hbuf, wq, MTOK, 1536, 512,
      nullptr, nullptr, nullptr, nullptr, qbuf, kbuf, vbuf);

  flash_kernel<<<dim3(16, 32), 256, 0, stream>>>(qbuf, kbuf, vbuf, rpb, attn);

  gemm512<1, 64><<<dim3(64, 8), 512, 0, stream>>>(attn, wp, MTOK, 512, 512,
      proj_b, x, x1, nullptr, nullptr, nullptr, nullptr);

  ln_kernel<<<2048, 256, 0, stream>>>(x1, n2w, n2b, h2in);

  gemm512<2, 128><<<dim3(64, 16), 512, 0, stream>>>(h2in, w1, MTOK, 2048, 512,
      fc1_b, nullptr, nullptr, gelu, nullptr, nullptr, nullptr);

  gemm512<1, 64><<<dim3(64, 8), 512, 0, stream>>>(gelu, w2, MTOK, 512, 2048,
      fc2_b, x1, outp, nullptr, nullptr, nullptr, nullptr);
}